// Round 14
// baseline (1059.700 us; speedup 1.0000x reference)
//
#include <hip/hip_runtime.h>
#include <hip/hip_fp16.h>

// GCNEncoder: two GCNConv(+relu) layers + global mean pool.
// N=50000 nodes, E=1.6M edges, 128 ch, 64 graphs.
// R14: fused CSR kernel (hist -> scan -> scatter -> bucket-sort in ONE
// 256-block x 1024-thr kernel with grid barriers; 256 blocks <= 256 CUs so
// co-residency is guaranteed). Fused two-stage pool (last-block trick).
// Dispatches 10 -> 7. k_agg unchanged (at its request/BW ceiling).

#define CH 128
#define BSH 7          // 128 nodes per bucket
#define CBLK 256       // fused-CSR blocks (<= #CUs: co-resident by construction)
#define CTHR 1024
#define MAXNB 512      // LDS histogram capacity (NB = ceil(N/128) = 391)
#define PCH 32         // pool chunks per graph
#define LDW 136        // Wt LDS stride

typedef __attribute__((ext_vector_type(8))) short bf16x8;
typedef __attribute__((ext_vector_type(4))) float f32x4;
typedef __attribute__((ext_vector_type(4))) unsigned uintx4;

static __device__ __forceinline__ unsigned short f2bf(float f) {
    unsigned u = __float_as_uint(f);
    unsigned r = (u + 0x7FFF + ((u >> 16) & 1)) >> 16;  // RNE
    return (unsigned short)r;
}
static __device__ __forceinline__ float bflo(unsigned v) { return __uint_as_float(v << 16); }
static __device__ __forceinline__ float bfhi(unsigned v) { return __uint_as_float(v & 0xFFFF0000u); }
static __device__ __forceinline__ float f16u(unsigned bits15) {
    __half_raw hr; hr.x = (unsigned short)(bits15 & 0x7FFF);
    return __half2float(*reinterpret_cast<__half*>(&hr));
}
static __device__ __forceinline__ unsigned u16f(float f) {  // f >= 0
    __half hh = __float2half(f);
    return (unsigned)(*reinterpret_cast<unsigned short*>(&hh)) & 0x7FFF;
}

// Grid barrier: monotonic counter; all CBLK blocks are co-resident (1/CU).
static __device__ __forceinline__ void gridbar(unsigned* bar, unsigned target) {
    __syncthreads();
    __threadfence();  // release: write back this block's stores (L2 wb, device scope)
    if (threadIdx.x == 0) {
        atomicAdd(bar, 1u);
        while (__hip_atomic_load(bar, __ATOMIC_RELAXED, __HIP_MEMORY_SCOPE_AGENT) < target)
            __builtin_amdgcn_s_sleep(8);
    }
    __syncthreads();
    __threadfence();  // acquire: invalidate stale cached lines
}

// ---- Fused CSR build: hist -> scan -> scatter -> bucket sort (+rowptr,dis) ----
__global__ __launch_bounds__(CTHR, 4) void k_csr(
        const int* __restrict__ row, const int* __restrict__ col,
        const float* __restrict__ ew,
        int* __restrict__ H, int* __restrict__ bsum, unsigned* __restrict__ bar,
        int2* __restrict__ pairs2, unsigned* __restrict__ epk,
        int* __restrict__ rowptr, float* __restrict__ dis,
        int E, int N, int NB, int chunk) {
    __shared__ int sd[CTHR];
    __shared__ int hist[MAXNB];
    __shared__ float wsum[128];
    __shared__ int pref[128];
    int t = threadIdx.x, blk = blockIdx.x;
    int s = blk * chunk, se = min(s + chunk, E);

    // ---- P1: per-chunk bucket histogram -> H[i*CBLK+blk]
    for (int i = t; i < NB; i += CTHR) hist[i] = 0;
    __syncthreads();
    for (int e = s + t; e < se; e += CTHR) atomicAdd(&hist[col[e] >> BSH], 1);
    __syncthreads();
    for (int i = t; i < NB; i += CTHR) H[(size_t)i * CBLK + blk] = hist[i];
    gridbar(bar, CBLK * 1);

    // ---- P2a: block-local exclusive scan of segment [blk*NB, blk*NB+NB)
    int base = blk * NB;
    int v = (t < NB) ? H[base + t] : 0;
    sd[t] = v;
    __syncthreads();
    for (int off = 1; off < CTHR; off <<= 1) {
        int u = (t >= off) ? sd[t - off] : 0;
        __syncthreads();
        sd[t] += u;
        __syncthreads();
    }
    int excl = sd[t] - v;
    if (t == CTHR - 1) bsum[blk] = sd[CTHR - 1];
    gridbar(bar, CBLK * 2);

    // ---- P2b: global offset = sum bsum[j<blk]; write scanned H
    sd[t] = (t < blk) ? bsum[t] : 0;
    __syncthreads();
    for (int off = CTHR / 2; off; off >>= 1) {
        if (t < off) sd[t] += sd[t + off];
        __syncthreads();
    }
    int goff = sd[0];
    __syncthreads();
    if (t < NB) H[base + t] = excl + goff;
    gridbar(bar, CBLK * 3);

    // ---- P3: scatter into bucket order via LDS cursors (disjoint regions)
    for (int i = t; i < NB; i += CTHR) hist[i] = H[(size_t)i * CBLK + blk];
    __syncthreads();
    for (int e = s + t; e < se; e += CTHR) {
        int c = col[e];
        int pos = atomicAdd(&hist[c >> BSH], 1);
        pairs2[pos] = make_int2(row[e] | ((c & 127) << 17), __float_as_int(ew[e]));
    }
    gridbar(bar, CBLK * 4);

    // ---- P4: per-bucket node sort + rowptr + dis (blocks loop over buckets)
    for (int b = blk; b < NB; b += CBLK) {
        int n0 = b << BSH;
        int bs = H[(size_t)b * CBLK];
        int be = (b + 1 < NB) ? H[(size_t)(b + 1) * CBLK] : E;
        if (t < 128) { pref[t] = 0; wsum[t] = 0.f; }
        __syncthreads();
        for (int e = bs + t; e < be; e += CTHR)
            atomicAdd(&pref[(unsigned)pairs2[e].x >> 17], 1);
        __syncthreads();
        int cnt0 = (t < 128) ? pref[t] : 0;
        for (int off = 1; off < 128; off <<= 1) {
            int u = 0;
            if (t < 128 && t >= off) u = pref[t - off];
            __syncthreads();
            if (t < 128) pref[t] += u;
            __syncthreads();
        }
        if (t < 128) {
            int ex = pref[t] - cnt0;
            int node = n0 + t;
            if (node < N) rowptr[node] = bs + ex;
            pref[t] = bs + ex;  // cursor
        }
        if (b == NB - 1 && t == 0) rowptr[N] = E;
        __syncthreads();
        for (int e = bs + t; e < be; e += CTHR) {
            int2 pr = pairs2[e];
            int li = (unsigned)pr.x >> 17;
            float w = __int_as_float(pr.y);
            int pos = atomicAdd(&pref[li], 1);
            epk[pos] = (unsigned)(pr.x & 0x1FFFF) | (u16f(w) << 17);
            atomicAdd(&wsum[li], w);
        }
        __syncthreads();
        if (t < 128 && n0 + t < N) dis[n0 + t] = rsqrtf(1.0f + wsum[t]);
        __syncthreads();
    }
}

// Y[N,128](bf16) = dis[r] * (X[N,128](f32) @ W) via bf16 MFMA.
__global__ __launch_bounds__(512) void k_gemm_f32(const float* __restrict__ X,
                                                  const float* __restrict__ W,
                                                  const float* __restrict__ dis,
                                                  unsigned short* __restrict__ Y, int N) {
    __shared__ unsigned short Wt[128 * LDW];
    int tid = threadIdx.x;
    for (int i = tid; i < 4096; i += 512) {  // i indexes float4 of W[k][c]
        float4 v = ((const float4*)W)[i];
        int k = i >> 5;
        int c = (i & 31) * 4;
        Wt[(c + 0) * LDW + k] = f2bf(v.x);
        Wt[(c + 1) * LDW + k] = f2bf(v.y);
        Wt[(c + 2) * LDW + k] = f2bf(v.z);
        Wt[(c + 3) * LDW + k] = f2bf(v.w);
    }
    __syncthreads();
    int w = tid >> 6, lane = tid & 63;
    int l15 = lane & 15, kg = lane >> 4;
    int r = blockIdx.x * 128 + w * 16 + l15;
    f32x4 acc[8];
#pragma unroll
    for (int ct = 0; ct < 8; ++ct) acc[ct] = (f32x4){0.f, 0.f, 0.f, 0.f};
#pragma unroll
    for (int kb = 0; kb < 128; kb += 32) {
        union { unsigned u[4]; bf16x8 v; } a;
        if (r < N) {
            const float4* xp = (const float4*)(X + (size_t)r * CH + kb + kg * 8);
            float4 x0 = xp[0], x1 = xp[1];
            a.u[0] = ((unsigned)f2bf(x0.y) << 16) | f2bf(x0.x);
            a.u[1] = ((unsigned)f2bf(x0.w) << 16) | f2bf(x0.z);
            a.u[2] = ((unsigned)f2bf(x1.y) << 16) | f2bf(x1.x);
            a.u[3] = ((unsigned)f2bf(x1.w) << 16) | f2bf(x1.z);
        } else {
            a.u[0] = a.u[1] = a.u[2] = a.u[3] = 0;
        }
#pragma unroll
        for (int ct = 0; ct < 8; ++ct) {
            bf16x8 b = *(const bf16x8*)&Wt[(ct * 16 + l15) * LDW + kb + kg * 8];
            acc[ct] = __builtin_amdgcn_mfma_f32_16x16x32_bf16(a.v, b, acc[ct], 0, 0, 0);
        }
    }
    int orow = blockIdx.x * 128 + w * 16 + kg * 4;
    float dv[4];
#pragma unroll
    for (int j = 0; j < 4; ++j) dv[j] = (orow + j < N) ? dis[orow + j] : 0.f;
#pragma unroll
    for (int ct = 0; ct < 8; ++ct) {
#pragma unroll
        for (int j = 0; j < 4; ++j) {
            int rr = orow + j;
            if (rr < N) Y[(size_t)rr * CH + ct * 16 + l15] = f2bf(acc[ct][j] * dv[j]);
        }
    }
}

// Y[N,128](bf16) = dis[r] * (Xb[N,128](bf16) @ W) via bf16 MFMA.
__global__ __launch_bounds__(512) void k_gemm_bf16(const unsigned short* __restrict__ Xb,
                                                   const float* __restrict__ W,
                                                   const float* __restrict__ dis,
                                                   unsigned short* __restrict__ Y, int N) {
    __shared__ unsigned short Wt[128 * LDW];
    int tid = threadIdx.x;
    for (int i = tid; i < 4096; i += 512) {
        float4 v = ((const float4*)W)[i];
        int k = i >> 5;
        int c = (i & 31) * 4;
        Wt[(c + 0) * LDW + k] = f2bf(v.x);
        Wt[(c + 1) * LDW + k] = f2bf(v.y);
        Wt[(c + 2) * LDW + k] = f2bf(v.z);
        Wt[(c + 3) * LDW + k] = f2bf(v.w);
    }
    __syncthreads();
    int w = tid >> 6, lane = tid & 63;
    int l15 = lane & 15, kg = lane >> 4;
    int r = blockIdx.x * 128 + w * 16 + l15;
    f32x4 acc[8];
#pragma unroll
    for (int ct = 0; ct < 8; ++ct) acc[ct] = (f32x4){0.f, 0.f, 0.f, 0.f};
#pragma unroll
    for (int kb = 0; kb < 128; kb += 32) {
        bf16x8 a;
        if (r < N) {
            a = *(const bf16x8*)&Xb[(size_t)r * CH + kb + kg * 8];
        } else {
            a = (bf16x8){0, 0, 0, 0, 0, 0, 0, 0};
        }
#pragma unroll
        for (int ct = 0; ct < 8; ++ct) {
            bf16x8 b = *(const bf16x8*)&Wt[(ct * 16 + l15) * LDW + kb + kg * 8];
            acc[ct] = __builtin_amdgcn_mfma_f32_16x16x32_bf16(a, b, acc[ct], 0, 0, 0);
        }
    }
    int orow = blockIdx.x * 128 + w * 16 + kg * 4;
    float dv[4];
#pragma unroll
    for (int j = 0; j < 4; ++j) dv[j] = (orow + j < N) ? dis[orow + j] : 0.f;
#pragma unroll
    for (int ct = 0; ct < 8; ++ct) {
#pragma unroll
        for (int j = 0; j < 4; ++j) {
            int rr = orow + j;
            if (rr < N) Y[(size_t)rr * CH + ct * 16 + l15] = f2bf(acc[ct][j] * dv[j]);
        }
    }
}

// One wave per node: sum = xw'[n] + sum_e w_e * xw'[src_e]; out = relu(dn*sum + b).
#define GATHER(p) XW[(size_t)((p) & 0x1FFFF) * 64 + lane]
#define ACC4(q, va, vb, vc, vd)                                              \
    {                                                                        \
        float na = f16u((q)[0] >> 17), nb = f16u((q)[1] >> 17);              \
        float nc = f16u((q)[2] >> 17), nd = f16u((q)[3] >> 17);              \
        ax += na * bflo(va) + nb * bflo(vb) + nc * bflo(vc) + nd * bflo(vd); \
        ay += na * bfhi(va) + nb * bfhi(vb) + nc * bfhi(vc) + nd * bfhi(vd); \
    }
template <bool OUT_BF16>
__global__ __launch_bounds__(64) void k_agg(const unsigned int* __restrict__ XW,
                                            const float* __restrict__ dis,
                                            const int* __restrict__ rowptr,
                                            const unsigned* __restrict__ epk,
                                            const float* __restrict__ bias,
                                            void* __restrict__ OUT, int N) {
    int n = blockIdx.x;
    if (n >= N) return;
    int lane = threadIdx.x;
    unsigned a = XW[(size_t)n * 64 + lane];
    float ax = bflo(a);
    float ay = bfhi(a);
    int e0 = rowptr[n], e1 = rowptr[n + 1];
    int e = e0;
    for (; e < e1 && (e & 3); ++e) {
        unsigned p = epk[e];
        unsigned v = GATHER(p);
        float nn = f16u(p >> 17);
        ax += nn * bflo(v);
        ay += nn * bfhi(v);
    }
    for (; e + 16 <= e1; e += 16) {
        uintx4 q0 = __builtin_nontemporal_load((const uintx4*)&epk[e]);
        uintx4 q1 = __builtin_nontemporal_load((const uintx4*)&epk[e + 4]);
        uintx4 q2 = __builtin_nontemporal_load((const uintx4*)&epk[e + 8]);
        uintx4 q3 = __builtin_nontemporal_load((const uintx4*)&epk[e + 12]);
        unsigned v0 = GATHER(q0[0]), v1 = GATHER(q0[1]), v2 = GATHER(q0[2]), v3 = GATHER(q0[3]);
        unsigned v4 = GATHER(q1[0]), v5 = GATHER(q1[1]), v6 = GATHER(q1[2]), v7 = GATHER(q1[3]);
        unsigned v8 = GATHER(q2[0]), v9 = GATHER(q2[1]), va = GATHER(q2[2]), vb = GATHER(q2[3]);
        unsigned vc = GATHER(q3[0]), vd = GATHER(q3[1]), ve = GATHER(q3[2]), vf = GATHER(q3[3]);
        ACC4(q0, v0, v1, v2, v3);
        ACC4(q1, v4, v5, v6, v7);
        ACC4(q2, v8, v9, va, vb);
        ACC4(q3, vc, vd, ve, vf);
    }
    for (; e + 4 <= e1; e += 4) {
        uintx4 q = __builtin_nontemporal_load((const uintx4*)&epk[e]);
        unsigned v0 = GATHER(q[0]), v1 = GATHER(q[1]), v2 = GATHER(q[2]), v3 = GATHER(q[3]);
        ACC4(q, v0, v1, v2, v3);
    }
    for (; e < e1; ++e) {
        unsigned p = epk[e];
        unsigned v = GATHER(p);
        float nn = f16u(p >> 17);
        ax += nn * bflo(v);
        ay += nn * bfhi(v);
    }
    float dn = dis[n];
    float2 b = ((const float2*)bias)[lane];
    ax = fmaxf(fmaf(dn, ax, b.x), 0.f);
    ay = fmaxf(fmaf(dn, ay, b.y), 0.f);
    if (OUT_BF16) {
        unsigned o = ((unsigned)f2bf(ay) << 16) | f2bf(ax);
        ((unsigned*)OUT)[(size_t)n * 64 + lane] = o;
    } else {
        ((float2*)OUT)[(size_t)n * 64 + lane] = make_float2(ax, ay);
    }
}

__device__ __forceinline__ int lowerb(const int* a, int n, int v) {
    int lo = 0, hi = n;
    while (lo < hi) {
        int m = (lo + hi) >> 1;
        if (a[m] < v) lo = m + 1; else hi = m;
    }
    return lo;
}

// Fused two-stage mean pool: 64*PCH partial blocks; last block reduces.
__global__ __launch_bounds__(128) void k_pool(const float* __restrict__ Hm,
                                              const int* __restrict__ batch,
                                              float* __restrict__ partial,
                                              float* __restrict__ P,
                                              unsigned* __restrict__ cnt2, int N) {
    __shared__ int ss[2];
    __shared__ int lastFlag;
    __shared__ int lb[65];
    int t = threadIdx.x;
    int g = blockIdx.x / PCH;
    int k = blockIdx.x % PCH;
    if (t == 0) {
        ss[0] = lowerb(batch, N, g);
        ss[1] = lowerb(batch, N, g + 1);
    }
    __syncthreads();
    int s = ss[0], len = ss[1] - ss[0];
    int cs = s + (int)(((long long)len * k) / PCH);
    int ce = s + (int)(((long long)len * (k + 1)) / PCH);
    float a0 = 0.f, a1 = 0.f;
    int n = cs;
    for (; n + 2 <= ce; n += 2) {
        a0 += Hm[(size_t)(n + 0) * CH + t];
        a1 += Hm[(size_t)(n + 1) * CH + t];
    }
    for (; n < ce; ++n) a0 += Hm[(size_t)n * CH + t];
    partial[(size_t)blockIdx.x * CH + t] = a0 + a1;
    __threadfence();
    if (t == 0) lastFlag = (atomicAdd(cnt2, 1u) == (unsigned)(64 * PCH - 1));
    __syncthreads();
    if (!lastFlag) return;
    __threadfence();  // acquire: see all partials
    if (t <= 64) lb[t] = lowerb(batch, N, t);
    __syncthreads();
    for (int gg = 0; gg < 64; ++gg) {
        float a = 0.f;
#pragma unroll
        for (int kk = 0; kk < PCH; ++kk) a += partial[(size_t)(gg * PCH + kk) * CH + t];
        float c = (float)(lb[gg + 1] - lb[gg]);
        P[(size_t)gg * CH + t] = a / fmaxf(c, 1.f);
    }
}

extern "C" void kernel_launch(void* const* d_in, const int* in_sizes, int n_in,
                              void* d_out, int out_size, void* d_ws, size_t ws_size,
                              hipStream_t stream) {
    const float* x     = (const float*)d_in[0];
    const int*   ei    = (const int*)d_in[1];
    const float* ew    = (const float*)d_in[2];
    const int*   batch = (const int*)d_in[3];
    const float* W1    = (const float*)d_in[4];
    const float* b1    = (const float*)d_in[5];
    const float* W2    = (const float*)d_in[6];
    const float* b2    = (const float*)d_in[7];

    int N = in_sizes[0] / CH;   // 50000
    int E = in_sizes[1] / 2;    // 1600000
    const int* row = ei;
    const int* col = ei + E;

    float* out    = (float*)d_out;
    float* h      = out;
    float* pooled = out + (size_t)N * CH;

    int NB    = (N + 127) >> BSH;            // 391
    int chunk = (E + CBLK - 1) / CBLK;       // 6250
    int n2    = NB * CBLK;                   // 100096

    // ws: bar(256B: bar@0, cnt2@64) | dis | rowptr | H | bsum | epk | bufA | bufB
    char* wsb = (char*)d_ws;
    size_t oBar = 256;
    size_t oN  = ((size_t)N * 4 + 255) & ~(size_t)255;
    size_t oN1 = ((size_t)(N + 1) * 4 + 255) & ~(size_t)255;
    size_t oH  = ((size_t)(n2 + 1) * 4 + 255) & ~(size_t)255;
    size_t oB  = 4096;
    size_t oE1 = ((size_t)E * 4 + 255) & ~(size_t)255;
    size_t oE2 = ((size_t)E * 8 + 255) & ~(size_t)255;  // 12.8MB (>= N*CH*2)
    unsigned* bar  = (unsigned*)wsb;
    unsigned* cnt2 = (unsigned*)(wsb + 64);
    float* dis    = (float*)(wsb + oBar);
    int*   rowptr = (int*)(wsb + oBar + oN);
    int*   H      = (int*)(wsb + oBar + oN + oN1);
    int*   bsum   = (int*)(wsb + oBar + oN + oN1 + oH);
    unsigned* epk = (unsigned*)(wsb + oBar + oN + oN1 + oH + oB);
    char*  bufA   = wsb + oBar + oN + oN1 + oH + oB + oE1;
    char*  bufB   = bufA + oE2;
    int2*  pairs2 = (int2*)bufA;                  // dead before gemm1 writes xw
    unsigned short* xw = (unsigned short*)bufA;
    unsigned short* h1 = (unsigned short*)bufB;
    float* partial = (float*)bufB;                // h1 dead after gemm2; 1MB << 12.8MB

    hipMemsetAsync(wsb, 0, 256, stream);  // bar + cnt2

    // ---- fused CSR build (one kernel, grid barriers) ----
    k_csr<<<CBLK, CTHR, 0, stream>>>(row, col, ew, H, bsum, bar, pairs2, epk,
                                     rowptr, dis, E, N, NB, chunk);

    int gb = (N + 127) / 128;
    // ---- layer 1 ----
    k_gemm_f32<<<gb, 512, 0, stream>>>(x, W1, dis, xw, N);
    k_agg<true><<<N, 64, 0, stream>>>((const unsigned int*)xw, dis, rowptr, epk, b1, h1, N);
    // ---- layer 2 ----
    k_gemm_bf16<<<gb, 512, 0, stream>>>(h1, W2, dis, xw, N);
    k_agg<false><<<N, 64, 0, stream>>>((const unsigned int*)xw, dis, rowptr, epk, b2, h, N);
    // ---- fused mean pool ----
    k_pool<<<64 * PCH, 128, 0, stream>>>(h, batch, partial, pooled, cnt2, N);
}

// Round 15
// 530.701 us; speedup vs baseline: 1.9968x; 1.9968x over previous
//
#include <hip/hip_runtime.h>
#include <hip/hip_fp16.h>

// GCNEncoder: two GCNConv(+relu) layers + global mean pool.
// N=50000 nodes, E=1.6M edges, 128 ch, 64 graphs.
// R15: revert R14's fused-CSR (software grid barriers = 620us vs ~40us of
// separate kernels — kernel-boundary sync is the cheap grid barrier on
// MI355X). Back to R13 structure + fused two-stage pool (last-block-done
// counter, same proven pattern as the fused scan). 9 dispatches.

#define CH 128
#define BSH 7         // 128 nodes per bucket
#define NBLK 1024     // level-1 edge-chunk blocks
#define MAXNB 512     // LDS histogram capacity (NB = ceil(N/128) = 391)
#define PCH 32        // pool chunks per graph
#define LDW 136       // Wt LDS stride

typedef __attribute__((ext_vector_type(8))) short bf16x8;
typedef __attribute__((ext_vector_type(4))) float f32x4;
typedef __attribute__((ext_vector_type(4))) unsigned uintx4;

static __device__ __forceinline__ unsigned short f2bf(float f) {
    unsigned u = __float_as_uint(f);
    unsigned r = (u + 0x7FFF + ((u >> 16) & 1)) >> 16;  // RNE
    return (unsigned short)r;
}
static __device__ __forceinline__ float bflo(unsigned v) { return __uint_as_float(v << 16); }
static __device__ __forceinline__ float bfhi(unsigned v) { return __uint_as_float(v & 0xFFFF0000u); }
static __device__ __forceinline__ float f16u(unsigned bits15) {
    __half_raw hr; hr.x = (unsigned short)(bits15 & 0x7FFF);
    return __half2float(*reinterpret_cast<__half*>(&hr));
}
static __device__ __forceinline__ unsigned u16f(float f) {  // f >= 0
    __half hh = __float2half(f);
    return (unsigned)(*reinterpret_cast<unsigned short*>(&hh)) & 0x7FFF;
}

// ---- level-1 count: per-(bucket, chunk-block) histogram, LDS atomics only
__global__ __launch_bounds__(256) void k_sort1a(const int* __restrict__ col,
                                                int* __restrict__ H, int* __restrict__ cnt,
                                                unsigned* __restrict__ cnt2,
                                                int E, int NB, int chunk) {
    __shared__ int hist[MAXNB];
    int t = threadIdx.x, blk = blockIdx.x;
    if (blk == 0 && t == 0) { *cnt = 0; *cnt2 = 0u; }  // reset last-block counters
    for (int i = t; i < NB; i += 256) hist[i] = 0;
    __syncthreads();
    int s = blk * chunk, e1 = min(s + chunk, E);
    for (int e = s + t; e < e1; e += 256) atomicAdd(&hist[col[e] >> BSH], 1);
    __syncthreads();
    for (int i = t; i < NB; i += 256) H[(size_t)i * NBLK + blk] = hist[i];
}

// ---- scan: block-local exclusive in place + last block scans bsum (fused phase 2)
__global__ __launch_bounds__(1024) void k_scan1(int* __restrict__ data,
                                                int* __restrict__ bsum,
                                                int* __restrict__ cnt, int n, int nb) {
    __shared__ int sd[1024];
    __shared__ int lastFlag;
    int t = threadIdx.x;
    int i = blockIdx.x * 1024 + t;
    int v = (i < n) ? data[i] : 0;
    sd[t] = v;
    __syncthreads();
    for (int off = 1; off < 1024; off <<= 1) {
        int u = (t >= off) ? sd[t - off] : 0;
        __syncthreads();
        sd[t] += u;
        __syncthreads();
    }
    if (i < n) data[i] = sd[t] - v;
    if (t == 1023) {
        bsum[blockIdx.x] = sd[1023];
        __threadfence();
        lastFlag = (atomicAdd(cnt, 1) == (int)gridDim.x - 1);
    }
    __syncthreads();
    if (lastFlag) {
        __threadfence();
        int v2 = (t < nb) ? bsum[t] : 0;
        sd[t] = v2;
        __syncthreads();
        for (int off = 1; off < 1024; off <<= 1) {
            int u = (t >= off) ? sd[t - off] : 0;
            __syncthreads();
            sd[t] += u;
            __syncthreads();
        }
        if (t < nb) bsum[t] = sd[t] - v2;
    }
}

// ---- level-1 scatter into bucket order via LDS cursors (disjoint regions)
__global__ __launch_bounds__(256) void k_sort1b(const int* __restrict__ row,
                                                const int* __restrict__ col,
                                                const float* __restrict__ ew,
                                                const int* __restrict__ Hs,
                                                const int* __restrict__ bsum,
                                                int2* __restrict__ pairs2,
                                                int E, int NB, int chunk) {
    __shared__ int cur[MAXNB];
    int t = threadIdx.x, blk = blockIdx.x;
    for (int i = t; i < NB; i += 256) cur[i] = Hs[(size_t)i * NBLK + blk] + bsum[i];
    __syncthreads();
    int s = blk * chunk, e1 = min(s + chunk, E);
    for (int e = s + t; e < e1; e += 256) {
        int c = col[e];
        int pos = atomicAdd(&cur[c >> BSH], 1);
        pairs2[pos] = make_int2(row[e] | ((c & 127) << 17), __float_as_int(ew[e]));
    }
}

// ---- level-2: per-bucket node sort + rowptr + degree (dis), LDS only.
// Output: epk[pos] = { f16(w):15 | src:17 } (4B per edge) — final form.
__global__ __launch_bounds__(256) void k_sort2(const int* __restrict__ Hs,
                                               const int* __restrict__ bsum,
                                               const int2* __restrict__ pairs2,
                                               unsigned* __restrict__ epk,
                                               int* __restrict__ rowptr,
                                               float* __restrict__ dis,
                                               int E, int N, int NB) {
    __shared__ int hist[128];
    __shared__ int pref[128];
    __shared__ float wsum[128];
    int b = blockIdx.x, t = threadIdx.x;
    int n0 = b << BSH;
    int s = Hs[(size_t)b * NBLK] + bsum[b];
    int e1 = (b + 1 < NB) ? Hs[(size_t)(b + 1) * NBLK] + bsum[b + 1] : E;
    if (t < 128) { hist[t] = 0; wsum[t] = 0.f; }
    __syncthreads();
    for (int e = s + t; e < e1; e += 256)
        atomicAdd(&hist[(unsigned)pairs2[e].x >> 17], 1);
    __syncthreads();
    if (t < 128) pref[t] = hist[t];
    __syncthreads();
    for (int off = 1; off < 128; off <<= 1) {
        int v = 0;
        if (t < 128 && t >= off) v = pref[t - off];
        __syncthreads();
        if (t < 128) pref[t] += v;
        __syncthreads();
    }
    if (t < 128) {
        int excl = pref[t] - hist[t];
        int node = n0 + t;
        if (node < N) rowptr[node] = s + excl;
        hist[t] = s + excl;  // cursor
    }
    if (b == NB - 1 && t == 0) rowptr[N] = E;
    __syncthreads();
    for (int e = s + t; e < e1; e += 256) {
        int2 pr = pairs2[e];
        int li = (unsigned)pr.x >> 17;
        float w = __int_as_float(pr.y);
        int pos = atomicAdd(&hist[li], 1);
        epk[pos] = (unsigned)(pr.x & 0x1FFFF) | (u16f(w) << 17);
        atomicAdd(&wsum[li], w);
    }
    __syncthreads();
    if (t < 128 && n0 + t < N) dis[n0 + t] = rsqrtf(1.0f + wsum[t]);
}

// Y[N,128](bf16) = dis[r] * (X[N,128](f32) @ W) via bf16 MFMA.
__global__ __launch_bounds__(512) void k_gemm_f32(const float* __restrict__ X,
                                                  const float* __restrict__ W,
                                                  const float* __restrict__ dis,
                                                  unsigned short* __restrict__ Y, int N) {
    __shared__ unsigned short Wt[128 * LDW];
    int tid = threadIdx.x;
    for (int i = tid; i < 4096; i += 512) {  // i indexes float4 of W[k][c]
        float4 v = ((const float4*)W)[i];
        int k = i >> 5;
        int c = (i & 31) * 4;
        Wt[(c + 0) * LDW + k] = f2bf(v.x);
        Wt[(c + 1) * LDW + k] = f2bf(v.y);
        Wt[(c + 2) * LDW + k] = f2bf(v.z);
        Wt[(c + 3) * LDW + k] = f2bf(v.w);
    }
    __syncthreads();
    int w = tid >> 6, lane = tid & 63;
    int l15 = lane & 15, kg = lane >> 4;
    int r = blockIdx.x * 128 + w * 16 + l15;
    f32x4 acc[8];
#pragma unroll
    for (int ct = 0; ct < 8; ++ct) acc[ct] = (f32x4){0.f, 0.f, 0.f, 0.f};
#pragma unroll
    for (int kb = 0; kb < 128; kb += 32) {
        union { unsigned u[4]; bf16x8 v; } a;
        if (r < N) {
            const float4* xp = (const float4*)(X + (size_t)r * CH + kb + kg * 8);
            float4 x0 = xp[0], x1 = xp[1];
            a.u[0] = ((unsigned)f2bf(x0.y) << 16) | f2bf(x0.x);
            a.u[1] = ((unsigned)f2bf(x0.w) << 16) | f2bf(x0.z);
            a.u[2] = ((unsigned)f2bf(x1.y) << 16) | f2bf(x1.x);
            a.u[3] = ((unsigned)f2bf(x1.w) << 16) | f2bf(x1.z);
        } else {
            a.u[0] = a.u[1] = a.u[2] = a.u[3] = 0;
        }
#pragma unroll
        for (int ct = 0; ct < 8; ++ct) {
            bf16x8 b = *(const bf16x8*)&Wt[(ct * 16 + l15) * LDW + kb + kg * 8];
            acc[ct] = __builtin_amdgcn_mfma_f32_16x16x32_bf16(a.v, b, acc[ct], 0, 0, 0);
        }
    }
    int orow = blockIdx.x * 128 + w * 16 + kg * 4;
    float dv[4];
#pragma unroll
    for (int j = 0; j < 4; ++j) dv[j] = (orow + j < N) ? dis[orow + j] : 0.f;
#pragma unroll
    for (int ct = 0; ct < 8; ++ct) {
#pragma unroll
        for (int j = 0; j < 4; ++j) {
            int rr = orow + j;
            if (rr < N) Y[(size_t)rr * CH + ct * 16 + l15] = f2bf(acc[ct][j] * dv[j]);
        }
    }
}

// Y[N,128](bf16) = dis[r] * (Xb[N,128](bf16) @ W) via bf16 MFMA.
__global__ __launch_bounds__(512) void k_gemm_bf16(const unsigned short* __restrict__ Xb,
                                                   const float* __restrict__ W,
                                                   const float* __restrict__ dis,
                                                   unsigned short* __restrict__ Y, int N) {
    __shared__ unsigned short Wt[128 * LDW];
    int tid = threadIdx.x;
    for (int i = tid; i < 4096; i += 512) {
        float4 v = ((const float4*)W)[i];
        int k = i >> 5;
        int c = (i & 31) * 4;
        Wt[(c + 0) * LDW + k] = f2bf(v.x);
        Wt[(c + 1) * LDW + k] = f2bf(v.y);
        Wt[(c + 2) * LDW + k] = f2bf(v.z);
        Wt[(c + 3) * LDW + k] = f2bf(v.w);
    }
    __syncthreads();
    int w = tid >> 6, lane = tid & 63;
    int l15 = lane & 15, kg = lane >> 4;
    int r = blockIdx.x * 128 + w * 16 + l15;
    f32x4 acc[8];
#pragma unroll
    for (int ct = 0; ct < 8; ++ct) acc[ct] = (f32x4){0.f, 0.f, 0.f, 0.f};
#pragma unroll
    for (int kb = 0; kb < 128; kb += 32) {
        bf16x8 a;
        if (r < N) {
            a = *(const bf16x8*)&Xb[(size_t)r * CH + kb + kg * 8];
        } else {
            a = (bf16x8){0, 0, 0, 0, 0, 0, 0, 0};
        }
#pragma unroll
        for (int ct = 0; ct < 8; ++ct) {
            bf16x8 b = *(const bf16x8*)&Wt[(ct * 16 + l15) * LDW + kb + kg * 8];
            acc[ct] = __builtin_amdgcn_mfma_f32_16x16x32_bf16(a, b, acc[ct], 0, 0, 0);
        }
    }
    int orow = blockIdx.x * 128 + w * 16 + kg * 4;
    float dv[4];
#pragma unroll
    for (int j = 0; j < 4; ++j) dv[j] = (orow + j < N) ? dis[orow + j] : 0.f;
#pragma unroll
    for (int ct = 0; ct < 8; ++ct) {
#pragma unroll
        for (int j = 0; j < 4; ++j) {
            int rr = orow + j;
            if (rr < N) Y[(size_t)rr * CH + ct * 16 + l15] = f2bf(acc[ct][j] * dv[j]);
        }
    }
}

// One wave per node: sum = xw'[n] + sum_e w_e * xw'[src_e]; out = relu(dn*sum + b).
#define GATHER(p) XW[(size_t)((p) & 0x1FFFF) * 64 + lane]
#define ACC4(q, va, vb, vc, vd)                                              \
    {                                                                        \
        float na = f16u((q)[0] >> 17), nb = f16u((q)[1] >> 17);              \
        float nc = f16u((q)[2] >> 17), nd = f16u((q)[3] >> 17);              \
        ax += na * bflo(va) + nb * bflo(vb) + nc * bflo(vc) + nd * bflo(vd); \
        ay += na * bfhi(va) + nb * bfhi(vb) + nc * bfhi(vc) + nd * bfhi(vd); \
    }
template <bool OUT_BF16>
__global__ __launch_bounds__(64) void k_agg(const unsigned int* __restrict__ XW,
                                            const float* __restrict__ dis,
                                            const int* __restrict__ rowptr,
                                            const unsigned* __restrict__ epk,
                                            const float* __restrict__ bias,
                                            void* __restrict__ OUT, int N) {
    int n = blockIdx.x;
    if (n >= N) return;
    int lane = threadIdx.x;
    unsigned a = XW[(size_t)n * 64 + lane];
    float ax = bflo(a);
    float ay = bfhi(a);
    int e0 = rowptr[n], e1 = rowptr[n + 1];
    int e = e0;
    for (; e < e1 && (e & 3); ++e) {
        unsigned p = epk[e];
        unsigned v = GATHER(p);
        float nn = f16u(p >> 17);
        ax += nn * bflo(v);
        ay += nn * bfhi(v);
    }
    for (; e + 16 <= e1; e += 16) {
        uintx4 q0 = __builtin_nontemporal_load((const uintx4*)&epk[e]);
        uintx4 q1 = __builtin_nontemporal_load((const uintx4*)&epk[e + 4]);
        uintx4 q2 = __builtin_nontemporal_load((const uintx4*)&epk[e + 8]);
        uintx4 q3 = __builtin_nontemporal_load((const uintx4*)&epk[e + 12]);
        unsigned v0 = GATHER(q0[0]), v1 = GATHER(q0[1]), v2 = GATHER(q0[2]), v3 = GATHER(q0[3]);
        unsigned v4 = GATHER(q1[0]), v5 = GATHER(q1[1]), v6 = GATHER(q1[2]), v7 = GATHER(q1[3]);
        unsigned v8 = GATHER(q2[0]), v9 = GATHER(q2[1]), va = GATHER(q2[2]), vb = GATHER(q2[3]);
        unsigned vc = GATHER(q3[0]), vd = GATHER(q3[1]), ve = GATHER(q3[2]), vf = GATHER(q3[3]);
        ACC4(q0, v0, v1, v2, v3);
        ACC4(q1, v4, v5, v6, v7);
        ACC4(q2, v8, v9, va, vb);
        ACC4(q3, vc, vd, ve, vf);
    }
    for (; e + 4 <= e1; e += 4) {
        uintx4 q = __builtin_nontemporal_load((const uintx4*)&epk[e]);
        unsigned v0 = GATHER(q[0]), v1 = GATHER(q[1]), v2 = GATHER(q[2]), v3 = GATHER(q[3]);
        ACC4(q, v0, v1, v2, v3);
    }
    for (; e < e1; ++e) {
        unsigned p = epk[e];
        unsigned v = GATHER(p);
        float nn = f16u(p >> 17);
        ax += nn * bflo(v);
        ay += nn * bfhi(v);
    }
    float dn = dis[n];
    float2 b = ((const float2*)bias)[lane];
    ax = fmaxf(fmaf(dn, ax, b.x), 0.f);
    ay = fmaxf(fmaf(dn, ay, b.y), 0.f);
    if (OUT_BF16) {
        unsigned o = ((unsigned)f2bf(ay) << 16) | f2bf(ax);
        ((unsigned*)OUT)[(size_t)n * 64 + lane] = o;
    } else {
        ((float2*)OUT)[(size_t)n * 64 + lane] = make_float2(ax, ay);
    }
}

__device__ __forceinline__ int lowerb(const int* a, int n, int v) {
    int lo = 0, hi = n;
    while (lo < hi) {
        int m = (lo + hi) >> 1;
        if (a[m] < v) lo = m + 1; else hi = m;
    }
    return lo;
}

// Fused two-stage mean pool: 64*PCH partial blocks; last block reduces.
__global__ __launch_bounds__(128) void k_pool(const float* __restrict__ Hm,
                                              const int* __restrict__ batch,
                                              float* __restrict__ partial,
                                              float* __restrict__ P,
                                              unsigned* __restrict__ cnt2, int N) {
    __shared__ int ss[2];
    __shared__ int lastFlag;
    __shared__ int lb[65];
    int t = threadIdx.x;
    int g = blockIdx.x / PCH;
    int k = blockIdx.x % PCH;
    if (t == 0) {
        ss[0] = lowerb(batch, N, g);
        ss[1] = lowerb(batch, N, g + 1);
    }
    __syncthreads();
    int s = ss[0], len = ss[1] - ss[0];
    int cs = s + (int)(((long long)len * k) / PCH);
    int ce = s + (int)(((long long)len * (k + 1)) / PCH);
    float a0 = 0.f, a1 = 0.f;
    int n = cs;
    for (; n + 2 <= ce; n += 2) {
        a0 += Hm[(size_t)(n + 0) * CH + t];
        a1 += Hm[(size_t)(n + 1) * CH + t];
    }
    for (; n < ce; ++n) a0 += Hm[(size_t)n * CH + t];
    partial[(size_t)blockIdx.x * CH + t] = a0 + a1;
    __threadfence();
    __syncthreads();
    if (t == 0) lastFlag = (atomicAdd(cnt2, 1u) == (unsigned)(64 * PCH - 1));
    __syncthreads();
    if (!lastFlag) return;
    __threadfence();  // acquire: see all partials
    if (t <= 64) lb[t] = lowerb(batch, N, t);
    __syncthreads();
    for (int gg = 0; gg < 64; ++gg) {
        float a = 0.f;
#pragma unroll
        for (int kk = 0; kk < PCH; ++kk) a += partial[(size_t)(gg * PCH + kk) * CH + t];
        float c = (float)(lb[gg + 1] - lb[gg]);
        P[(size_t)gg * CH + t] = a / fmaxf(c, 1.f);
    }
}

extern "C" void kernel_launch(void* const* d_in, const int* in_sizes, int n_in,
                              void* d_out, int out_size, void* d_ws, size_t ws_size,
                              hipStream_t stream) {
    const float* x     = (const float*)d_in[0];
    const int*   ei    = (const int*)d_in[1];
    const float* ew    = (const float*)d_in[2];
    const int*   batch = (const int*)d_in[3];
    const float* W1    = (const float*)d_in[4];
    const float* b1    = (const float*)d_in[5];
    const float* W2    = (const float*)d_in[6];
    const float* b2    = (const float*)d_in[7];

    int N = in_sizes[0] / CH;   // 50000
    int E = in_sizes[1] / 2;    // 1600000
    const int* row = ei;
    const int* col = ei + E;

    float* out    = (float*)d_out;
    float* h      = out;
    float* pooled = out + (size_t)N * CH;

    int NB    = (N + 127) >> BSH;          // 391
    int chunk = (E + NBLK - 1) / NBLK;     // 1563
    int n2    = NB * NBLK;                 // 400384

    // ws: dis | rowptr | H(n2+1; partial aliases) | bsum+cnt+cnt2 | epk | bufA | bufB
    char* wsb = (char*)d_ws;
    size_t oN  = ((size_t)N * 4 + 255) & ~(size_t)255;
    size_t oN1 = ((size_t)(N + 1) * 4 + 255) & ~(size_t)255;
    size_t oH  = ((size_t)(n2 + 1) * 4 + 255) & ~(size_t)255;
    size_t oB  = 8192;
    size_t oE1 = ((size_t)E * 4 + 255) & ~(size_t)255;
    size_t oE2 = ((size_t)E * 8 + 255) & ~(size_t)255;  // 12.8MB (>= N*CH*2)
    float* dis    = (float*)wsb;
    int*   rowptr = (int*)(wsb + oN);
    int*   H      = (int*)(wsb + oN + oN1);
    int*   bsum   = (int*)(wsb + oN + oN1 + oH);
    int*   cnt    = bsum + 1024;
    unsigned* cnt2 = (unsigned*)(bsum + 1056);
    unsigned* epk = (unsigned*)(wsb + oN + oN1 + oH + oB);
    char*  bufA   = wsb + oN + oN1 + oH + oB + oE1;
    char*  bufB   = bufA + oE2;
    int2*  pairs2 = (int2*)bufA;
    unsigned short* xw = (unsigned short*)bufA;
    unsigned short* h1 = (unsigned short*)bufB;
    float* partial = (float*)H;    // H dead after sort2; 1MB <= 1.6MB

    int sb2 = (n2 + 1023) / 1024;  // 391

    // ---- CSR build: two-level LDS counting sort (no global atomics) ----
    k_sort1a<<<NBLK, 256, 0, stream>>>(col, H, cnt, cnt2, E, NB, chunk);
    k_scan1<<<sb2, 1024, 0, stream>>>(H, bsum, cnt, n2, sb2);
    k_sort1b<<<NBLK, 256, 0, stream>>>(row, col, ew, H, bsum, pairs2, E, NB, chunk);
    k_sort2<<<NB, 256, 0, stream>>>(H, bsum, pairs2, epk, rowptr, dis, E, N, NB);

    int gb = (N + 127) / 128;
    // ---- layer 1 ----
    k_gemm_f32<<<gb, 512, 0, stream>>>(x, W1, dis, xw, N);
    k_agg<true><<<N, 64, 0, stream>>>((const unsigned int*)xw, dis, rowptr, epk, b1, h1, N);
    // ---- layer 2 ----
    k_gemm_bf16<<<gb, 512, 0, stream>>>(h1, W2, dis, xw, N);
    k_agg<false><<<N, 64, 0, stream>>>((const unsigned int*)xw, dis, rowptr, epk, b2, h, N);
    // ---- fused mean pool (last-block-done reduce) ----
    k_pool<<<64 * PCH, 128, 0, stream>>>(h, batch, partial, pooled, cnt2, N);
}

// Round 16
// 224.225 us; speedup vs baseline: 4.7260x; 2.3668x over previous
//
#include <hip/hip_runtime.h>
#include <hip/hip_fp16.h>

// GCNEncoder: two GCNConv(+relu) layers + global mean pool.
// N=50000 nodes, E=1.6M edges, 128 ch, 64 graphs.
// R16: restore R13 verbatim (best: 225.3us). R15's fused pool regressed
// (340us: per-block device-scope threadfence x2048 while ~25MB dirty in
// per-XCD L2s = writeback storm). Lesson (with R14): kernel-boundary sync
// is the ONLY cheap grid-wide sync on MI355X; never fence per-block at scale.
// Structure: 2-level LDS counting-sort CSR (fused scan), factored norm
// (xw' = dis[r]*(X@W)[r] in MFMA-GEMM epilogue), packed 4B edges
// {f16 w | src17}, 1-wave-per-node agg (request-bound ceiling, R10/R11),
// bf16 h1, two-stage pool.

#define CH 128
#define BSH 7         // 128 nodes per bucket
#define NBLK 1024     // level-1 edge-chunk blocks
#define MAXNB 512     // LDS histogram capacity (NB = ceil(N/128) = 391)
#define PCH 32        // pool chunks per graph
#define LDW 136       // Wt LDS stride

typedef __attribute__((ext_vector_type(8))) short bf16x8;
typedef __attribute__((ext_vector_type(4))) float f32x4;
typedef __attribute__((ext_vector_type(4))) unsigned uintx4;

static __device__ __forceinline__ unsigned short f2bf(float f) {
    unsigned u = __float_as_uint(f);
    unsigned r = (u + 0x7FFF + ((u >> 16) & 1)) >> 16;  // RNE
    return (unsigned short)r;
}
static __device__ __forceinline__ float bflo(unsigned v) { return __uint_as_float(v << 16); }
static __device__ __forceinline__ float bfhi(unsigned v) { return __uint_as_float(v & 0xFFFF0000u); }
static __device__ __forceinline__ float f16u(unsigned bits15) {
    __half_raw hr; hr.x = (unsigned short)(bits15 & 0x7FFF);
    return __half2float(*reinterpret_cast<__half*>(&hr));
}
static __device__ __forceinline__ unsigned u16f(float f) {  // f >= 0
    __half hh = __float2half(f);
    return (unsigned)(*reinterpret_cast<unsigned short*>(&hh)) & 0x7FFF;
}

// ---- level-1 count: per-(bucket, chunk-block) histogram, LDS atomics only
__global__ __launch_bounds__(256) void k_sort1a(const int* __restrict__ col,
                                                int* __restrict__ H, int* __restrict__ cnt,
                                                int E, int NB, int chunk) {
    __shared__ int hist[MAXNB];
    int t = threadIdx.x, blk = blockIdx.x;
    if (blk == 0 && t == 0) *cnt = 0;  // reset scan1's last-block counter
    for (int i = t; i < NB; i += 256) hist[i] = 0;
    __syncthreads();
    int s = blk * chunk, e1 = min(s + chunk, E);
    for (int e = s + t; e < e1; e += 256) atomicAdd(&hist[col[e] >> BSH], 1);
    __syncthreads();
    for (int i = t; i < NB; i += 256) H[(size_t)i * NBLK + blk] = hist[i];
}

// ---- scan: block-local exclusive in place + last block scans bsum (fused phase 2)
__global__ __launch_bounds__(1024) void k_scan1(int* __restrict__ data,
                                                int* __restrict__ bsum,
                                                int* __restrict__ cnt, int n, int nb) {
    __shared__ int sd[1024];
    __shared__ int lastFlag;
    int t = threadIdx.x;
    int i = blockIdx.x * 1024 + t;
    int v = (i < n) ? data[i] : 0;
    sd[t] = v;
    __syncthreads();
    for (int off = 1; off < 1024; off <<= 1) {
        int u = (t >= off) ? sd[t - off] : 0;
        __syncthreads();
        sd[t] += u;
        __syncthreads();
    }
    if (i < n) data[i] = sd[t] - v;
    if (t == 1023) {
        bsum[blockIdx.x] = sd[1023];
        __threadfence();
        lastFlag = (atomicAdd(cnt, 1) == (int)gridDim.x - 1);
    }
    __syncthreads();
    if (lastFlag) {
        __threadfence();
        int v2 = (t < nb) ? bsum[t] : 0;
        sd[t] = v2;
        __syncthreads();
        for (int off = 1; off < 1024; off <<= 1) {
            int u = (t >= off) ? sd[t - off] : 0;
            __syncthreads();
            sd[t] += u;
            __syncthreads();
        }
        if (t < nb) bsum[t] = sd[t] - v2;
    }
}

// ---- level-1 scatter into bucket order via LDS cursors (disjoint regions)
__global__ __launch_bounds__(256) void k_sort1b(const int* __restrict__ row,
                                                const int* __restrict__ col,
                                                const float* __restrict__ ew,
                                                const int* __restrict__ Hs,
                                                const int* __restrict__ bsum,
                                                int2* __restrict__ pairs2,
                                                int E, int NB, int chunk) {
    __shared__ int cur[MAXNB];
    int t = threadIdx.x, blk = blockIdx.x;
    for (int i = t; i < NB; i += 256) cur[i] = Hs[(size_t)i * NBLK + blk] + bsum[i];
    __syncthreads();
    int s = blk * chunk, e1 = min(s + chunk, E);
    for (int e = s + t; e < e1; e += 256) {
        int c = col[e];
        int pos = atomicAdd(&cur[c >> BSH], 1);
        pairs2[pos] = make_int2(row[e] | ((c & 127) << 17), __float_as_int(ew[e]));
    }
}

// ---- level-2: per-bucket node sort + rowptr + degree (dis), LDS only.
// Output: epk[pos] = { f16(w):15 | src:17 } (4B per edge) — final form.
__global__ __launch_bounds__(256) void k_sort2(const int* __restrict__ Hs,
                                               const int* __restrict__ bsum,
                                               const int2* __restrict__ pairs2,
                                               unsigned* __restrict__ epk,
                                               int* __restrict__ rowptr,
                                               float* __restrict__ dis,
                                               int E, int N, int NB) {
    __shared__ int hist[128];
    __shared__ int pref[128];
    __shared__ float wsum[128];
    int b = blockIdx.x, t = threadIdx.x;
    int n0 = b << BSH;
    int s = Hs[(size_t)b * NBLK] + bsum[b];
    int e1 = (b + 1 < NB) ? Hs[(size_t)(b + 1) * NBLK] + bsum[b + 1] : E;
    if (t < 128) { hist[t] = 0; wsum[t] = 0.f; }
    __syncthreads();
    for (int e = s + t; e < e1; e += 256)
        atomicAdd(&hist[(unsigned)pairs2[e].x >> 17], 1);
    __syncthreads();
    if (t < 128) pref[t] = hist[t];
    __syncthreads();
    for (int off = 1; off < 128; off <<= 1) {
        int v = 0;
        if (t < 128 && t >= off) v = pref[t - off];
        __syncthreads();
        if (t < 128) pref[t] += v;
        __syncthreads();
    }
    if (t < 128) {
        int excl = pref[t] - hist[t];
        int node = n0 + t;
        if (node < N) rowptr[node] = s + excl;
        hist[t] = s + excl;  // cursor
    }
    if (b == NB - 1 && t == 0) rowptr[N] = E;
    __syncthreads();
    for (int e = s + t; e < e1; e += 256) {
        int2 pr = pairs2[e];
        int li = (unsigned)pr.x >> 17;
        float w = __int_as_float(pr.y);
        int pos = atomicAdd(&hist[li], 1);
        epk[pos] = (unsigned)(pr.x & 0x1FFFF) | (u16f(w) << 17);
        atomicAdd(&wsum[li], w);
    }
    __syncthreads();
    if (t < 128 && n0 + t < N) dis[n0 + t] = rsqrtf(1.0f + wsum[t]);
}

// Y[N,128](bf16) = dis[r] * (X[N,128](f32) @ W) via bf16 MFMA.
__global__ __launch_bounds__(512) void k_gemm_f32(const float* __restrict__ X,
                                                  const float* __restrict__ W,
                                                  const float* __restrict__ dis,
                                                  unsigned short* __restrict__ Y, int N) {
    __shared__ unsigned short Wt[128 * LDW];
    int tid = threadIdx.x;
    for (int i = tid; i < 4096; i += 512) {  // i indexes float4 of W[k][c]
        float4 v = ((const float4*)W)[i];
        int k = i >> 5;
        int c = (i & 31) * 4;
        Wt[(c + 0) * LDW + k] = f2bf(v.x);
        Wt[(c + 1) * LDW + k] = f2bf(v.y);
        Wt[(c + 2) * LDW + k] = f2bf(v.z);
        Wt[(c + 3) * LDW + k] = f2bf(v.w);
    }
    __syncthreads();
    int w = tid >> 6, lane = tid & 63;
    int l15 = lane & 15, kg = lane >> 4;
    int r = blockIdx.x * 128 + w * 16 + l15;
    f32x4 acc[8];
#pragma unroll
    for (int ct = 0; ct < 8; ++ct) acc[ct] = (f32x4){0.f, 0.f, 0.f, 0.f};
#pragma unroll
    for (int kb = 0; kb < 128; kb += 32) {
        union { unsigned u[4]; bf16x8 v; } a;
        if (r < N) {
            const float4* xp = (const float4*)(X + (size_t)r * CH + kb + kg * 8);
            float4 x0 = xp[0], x1 = xp[1];
            a.u[0] = ((unsigned)f2bf(x0.y) << 16) | f2bf(x0.x);
            a.u[1] = ((unsigned)f2bf(x0.w) << 16) | f2bf(x0.z);
            a.u[2] = ((unsigned)f2bf(x1.y) << 16) | f2bf(x1.x);
            a.u[3] = ((unsigned)f2bf(x1.w) << 16) | f2bf(x1.z);
        } else {
            a.u[0] = a.u[1] = a.u[2] = a.u[3] = 0;
        }
#pragma unroll
        for (int ct = 0; ct < 8; ++ct) {
            bf16x8 b = *(const bf16x8*)&Wt[(ct * 16 + l15) * LDW + kb + kg * 8];
            acc[ct] = __builtin_amdgcn_mfma_f32_16x16x32_bf16(a.v, b, acc[ct], 0, 0, 0);
        }
    }
    int orow = blockIdx.x * 128 + w * 16 + kg * 4;
    float dv[4];
#pragma unroll
    for (int j = 0; j < 4; ++j) dv[j] = (orow + j < N) ? dis[orow + j] : 0.f;
#pragma unroll
    for (int ct = 0; ct < 8; ++ct) {
#pragma unroll
        for (int j = 0; j < 4; ++j) {
            int rr = orow + j;
            if (rr < N) Y[(size_t)rr * CH + ct * 16 + l15] = f2bf(acc[ct][j] * dv[j]);
        }
    }
}

// Y[N,128](bf16) = dis[r] * (Xb[N,128](bf16) @ W) via bf16 MFMA.
__global__ __launch_bounds__(512) void k_gemm_bf16(const unsigned short* __restrict__ Xb,
                                                   const float* __restrict__ W,
                                                   const float* __restrict__ dis,
                                                   unsigned short* __restrict__ Y, int N) {
    __shared__ unsigned short Wt[128 * LDW];
    int tid = threadIdx.x;
    for (int i = tid; i < 4096; i += 512) {
        float4 v = ((const float4*)W)[i];
        int k = i >> 5;
        int c = (i & 31) * 4;
        Wt[(c + 0) * LDW + k] = f2bf(v.x);
        Wt[(c + 1) * LDW + k] = f2bf(v.y);
        Wt[(c + 2) * LDW + k] = f2bf(v.z);
        Wt[(c + 3) * LDW + k] = f2bf(v.w);
    }
    __syncthreads();
    int w = tid >> 6, lane = tid & 63;
    int l15 = lane & 15, kg = lane >> 4;
    int r = blockIdx.x * 128 + w * 16 + l15;
    f32x4 acc[8];
#pragma unroll
    for (int ct = 0; ct < 8; ++ct) acc[ct] = (f32x4){0.f, 0.f, 0.f, 0.f};
#pragma unroll
    for (int kb = 0; kb < 128; kb += 32) {
        bf16x8 a;
        if (r < N) {
            a = *(const bf16x8*)&Xb[(size_t)r * CH + kb + kg * 8];
        } else {
            a = (bf16x8){0, 0, 0, 0, 0, 0, 0, 0};
        }
#pragma unroll
        for (int ct = 0; ct < 8; ++ct) {
            bf16x8 b = *(const bf16x8*)&Wt[(ct * 16 + l15) * LDW + kb + kg * 8];
            acc[ct] = __builtin_amdgcn_mfma_f32_16x16x32_bf16(a, b, acc[ct], 0, 0, 0);
        }
    }
    int orow = blockIdx.x * 128 + w * 16 + kg * 4;
    float dv[4];
#pragma unroll
    for (int j = 0; j < 4; ++j) dv[j] = (orow + j < N) ? dis[orow + j] : 0.f;
#pragma unroll
    for (int ct = 0; ct < 8; ++ct) {
#pragma unroll
        for (int j = 0; j < 4; ++j) {
            int rr = orow + j;
            if (rr < N) Y[(size_t)rr * CH + ct * 16 + l15] = f2bf(acc[ct][j] * dv[j]);
        }
    }
}

// One wave per node: sum = xw'[n] + sum_e w_e * xw'[src_e]; out = relu(dn*sum + b).
#define GATHER(p) XW[(size_t)((p) & 0x1FFFF) * 64 + lane]
#define ACC4(q, va, vb, vc, vd)                                              \
    {                                                                        \
        float na = f16u((q)[0] >> 17), nb = f16u((q)[1] >> 17);              \
        float nc = f16u((q)[2] >> 17), nd = f16u((q)[3] >> 17);              \
        ax += na * bflo(va) + nb * bflo(vb) + nc * bflo(vc) + nd * bflo(vd); \
        ay += na * bfhi(va) + nb * bfhi(vb) + nc * bfhi(vc) + nd * bfhi(vd); \
    }
template <bool OUT_BF16>
__global__ __launch_bounds__(64) void k_agg(const unsigned int* __restrict__ XW,
                                            const float* __restrict__ dis,
                                            const int* __restrict__ rowptr,
                                            const unsigned* __restrict__ epk,
                                            const float* __restrict__ bias,
                                            void* __restrict__ OUT, int N) {
    int n = blockIdx.x;
    if (n >= N) return;
    int lane = threadIdx.x;
    unsigned a = XW[(size_t)n * 64 + lane];
    float ax = bflo(a);
    float ay = bfhi(a);
    int e0 = rowptr[n], e1 = rowptr[n + 1];
    int e = e0;
    for (; e < e1 && (e & 3); ++e) {
        unsigned p = epk[e];
        unsigned v = GATHER(p);
        float nn = f16u(p >> 17);
        ax += nn * bflo(v);
        ay += nn * bfhi(v);
    }
    for (; e + 16 <= e1; e += 16) {
        uintx4 q0 = __builtin_nontemporal_load((const uintx4*)&epk[e]);
        uintx4 q1 = __builtin_nontemporal_load((const uintx4*)&epk[e + 4]);
        uintx4 q2 = __builtin_nontemporal_load((const uintx4*)&epk[e + 8]);
        uintx4 q3 = __builtin_nontemporal_load((const uintx4*)&epk[e + 12]);
        unsigned v0 = GATHER(q0[0]), v1 = GATHER(q0[1]), v2 = GATHER(q0[2]), v3 = GATHER(q0[3]);
        unsigned v4 = GATHER(q1[0]), v5 = GATHER(q1[1]), v6 = GATHER(q1[2]), v7 = GATHER(q1[3]);
        unsigned v8 = GATHER(q2[0]), v9 = GATHER(q2[1]), va = GATHER(q2[2]), vb = GATHER(q2[3]);
        unsigned vc = GATHER(q3[0]), vd = GATHER(q3[1]), ve = GATHER(q3[2]), vf = GATHER(q3[3]);
        ACC4(q0, v0, v1, v2, v3);
        ACC4(q1, v4, v5, v6, v7);
        ACC4(q2, v8, v9, va, vb);
        ACC4(q3, vc, vd, ve, vf);
    }
    for (; e + 4 <= e1; e += 4) {
        uintx4 q = __builtin_nontemporal_load((const uintx4*)&epk[e]);
        unsigned v0 = GATHER(q[0]), v1 = GATHER(q[1]), v2 = GATHER(q[2]), v3 = GATHER(q[3]);
        ACC4(q, v0, v1, v2, v3);
    }
    for (; e < e1; ++e) {
        unsigned p = epk[e];
        unsigned v = GATHER(p);
        float nn = f16u(p >> 17);
        ax += nn * bflo(v);
        ay += nn * bfhi(v);
    }
    float dn = dis[n];
    float2 b = ((const float2*)bias)[lane];
    ax = fmaxf(fmaf(dn, ax, b.x), 0.f);
    ay = fmaxf(fmaf(dn, ay, b.y), 0.f);
    if (OUT_BF16) {
        unsigned o = ((unsigned)f2bf(ay) << 16) | f2bf(ax);
        ((unsigned*)OUT)[(size_t)n * 64 + lane] = o;
    } else {
        ((float2*)OUT)[(size_t)n * 64 + lane] = make_float2(ax, ay);
    }
}

__device__ __forceinline__ int lowerb(const int* a, int n, int v) {
    int lo = 0, hi = n;
    while (lo < hi) {
        int m = (lo + hi) >> 1;
        if (a[m] < v) lo = m + 1; else hi = m;
    }
    return lo;
}

// Stage 1: 64 graphs x PCH chunks, partial channel sums.
__global__ __launch_bounds__(128) void k_pool1(const float* __restrict__ H,
                                               const int* __restrict__ batch,
                                               float* __restrict__ partial, int N) {
    __shared__ int ss[2];
    int g = blockIdx.x / PCH;
    int k = blockIdx.x % PCH;
    if (threadIdx.x == 0) {
        ss[0] = lowerb(batch, N, g);
        ss[1] = lowerb(batch, N, g + 1);
    }
    __syncthreads();
    int s = ss[0], len = ss[1] - ss[0];
    int cs = s + (int)(((long long)len * k) / PCH);
    int ce = s + (int)(((long long)len * (k + 1)) / PCH);
    int ch = threadIdx.x;
    float a0 = 0.f, a1 = 0.f;
    int n = cs;
    for (; n + 2 <= ce; n += 2) {
        a0 += H[(size_t)(n + 0) * CH + ch];
        a1 += H[(size_t)(n + 1) * CH + ch];
    }
    for (; n < ce; ++n) a0 += H[(size_t)n * CH + ch];
    partial[(size_t)blockIdx.x * CH + ch] = a0 + a1;
}

// Stage 2: reduce PCH partials per graph, divide by count.
__global__ __launch_bounds__(128) void k_pool2(const float* __restrict__ partial,
                                               const int* __restrict__ batch,
                                               float* __restrict__ P, int N) {
    __shared__ int ss[2];
    int g = blockIdx.x;
    if (threadIdx.x == 0) {
        ss[0] = lowerb(batch, N, g);
        ss[1] = lowerb(batch, N, g + 1);
    }
    __syncthreads();
    int ch = threadIdx.x;
    float a = 0.f;
#pragma unroll
    for (int k = 0; k < PCH; ++k) a += partial[(size_t)(g * PCH + k) * CH + ch];
    float c = (float)(ss[1] - ss[0]);
    P[(size_t)g * CH + ch] = a / fmaxf(c, 1.f);
}

extern "C" void kernel_launch(void* const* d_in, const int* in_sizes, int n_in,
                              void* d_out, int out_size, void* d_ws, size_t ws_size,
                              hipStream_t stream) {
    const float* x     = (const float*)d_in[0];
    const int*   ei    = (const int*)d_in[1];
    const float* ew    = (const float*)d_in[2];
    const int*   batch = (const int*)d_in[3];
    const float* W1    = (const float*)d_in[4];
    const float* b1    = (const float*)d_in[5];
    const float* W2    = (const float*)d_in[6];
    const float* b2    = (const float*)d_in[7];

    int N = in_sizes[0] / CH;   // 50000
    int E = in_sizes[1] / 2;    // 1600000
    const int* row = ei;
    const int* col = ei + E;

    float* out    = (float*)d_out;
    float* h      = out;
    float* pooled = out + (size_t)N * CH;

    int NB    = (N + 127) >> BSH;          // 391
    int chunk = (E + NBLK - 1) / NBLK;     // 1563
    int n2    = NB * NBLK;                 // 400384

    // ws: dis | rowptr | H(n2+1; partial aliases) | bsum+cnt | epk | bufA | bufB
    char* wsb = (char*)d_ws;
    size_t oN  = ((size_t)N * 4 + 255) & ~(size_t)255;
    size_t oN1 = ((size_t)(N + 1) * 4 + 255) & ~(size_t)255;
    size_t oH  = ((size_t)(n2 + 1) * 4 + 255) & ~(size_t)255;
    size_t oB  = 8192;
    size_t oE1 = ((size_t)E * 4 + 255) & ~(size_t)255;
    size_t oE2 = ((size_t)E * 8 + 255) & ~(size_t)255;  // 12.8MB (>= N*CH*2)
    float* dis    = (float*)wsb;
    int*   rowptr = (int*)(wsb + oN);
    int*   H      = (int*)(wsb + oN + oN1);
    int*   bsum   = (int*)(wsb + oN + oN1 + oH);
    int*   cnt    = bsum + 1024;
    unsigned* epk = (unsigned*)(wsb + oN + oN1 + oH + oB);
    char*  bufA   = wsb + oN + oN1 + oH + oB + oE1;
    char*  bufB   = bufA + oE2;
    int2*  pairs2 = (int2*)bufA;
    unsigned short* xw = (unsigned short*)bufA;
    unsigned short* h1 = (unsigned short*)bufB;
    float* partial = (float*)H;    // H dead after sort2; 1MB <= 1.6MB

    int sb2 = (n2 + 1023) / 1024;  // 391

    // ---- CSR build: two-level LDS counting sort (no global atomics) ----
    k_sort1a<<<NBLK, 256, 0, stream>>>(col, H, cnt, E, NB, chunk);
    k_scan1<<<sb2, 1024, 0, stream>>>(H, bsum, cnt, n2, sb2);
    k_sort1b<<<NBLK, 256, 0, stream>>>(row, col, ew, H, bsum, pairs2, E, NB, chunk);
    k_sort2<<<NB, 256, 0, stream>>>(H, bsum, pairs2, epk, rowptr, dis, E, N, NB);

    int gb = (N + 127) / 128;
    // ---- layer 1 ----
    k_gemm_f32<<<gb, 512, 0, stream>>>(x, W1, dis, xw, N);
    k_agg<true><<<N, 64, 0, stream>>>((const unsigned int*)xw, dis, rowptr, epk, b1, h1, N);
    // ---- layer 2 ----
    k_gemm_bf16<<<gb, 512, 0, stream>>>(h1, W2, dis, xw, N);
    k_agg<false><<<N, 64, 0, stream>>>((const unsigned int*)xw, dis, rowptr, epk, b2, h, N);
    // ---- mean pool (two-stage) ----
    k_pool1<<<64 * PCH, 128, 0, stream>>>(h, batch, partial, N);
    k_pool2<<<64, 128, 0, stream>>>(partial, batch, pooled, N);
}